// Round 1
// baseline (3768.238 us; speedup 1.0000x reference)
//
#include <hip/hip_runtime.h>
#include <hip/hip_bf16.h>
#include <math.h>

#define N_NODES 50000
#define N_EDGES 800000
#define FEAT 256
#define HID 256
#define OUTC 40
#define N_BATCH 10000

// ---------------- GEMM1: h1 = feat @ W1 + b1   [50000,256]x[256,256] ----------------
__global__ __launch_bounds__(256) void gemm1_kernel(const float* __restrict__ A,
                                                    const float* __restrict__ B,
                                                    const float* __restrict__ bias,
                                                    float* __restrict__ C, int M) {
    __shared__ float As[16][65];
    __shared__ float Bs[16][65];
    int tx = threadIdx.x & 15;
    int ty = threadIdx.x >> 4;
    int row0 = blockIdx.x * 64;
    int col0 = blockIdx.y * 64;
    float acc[4][4] = {};
    for (int k0 = 0; k0 < 256; k0 += 16) {
        #pragma unroll
        for (int i = 0; i < 4; i++) {
            int idx = threadIdx.x + i * 256;   // 0..1023
            int r = idx >> 4;                  // 0..63 row in tile
            int kk = idx & 15;                 // k in tile
            int gr = row0 + r;
            As[kk][r] = (gr < M) ? A[gr * 256 + k0 + kk] : 0.f;
        }
        #pragma unroll
        for (int i = 0; i < 4; i++) {
            int idx = threadIdx.x + i * 256;
            int r = idx >> 6;                  // k 0..15
            int cc = idx & 63;                 // col 0..63
            Bs[r][cc] = B[(k0 + r) * 256 + col0 + cc];
        }
        __syncthreads();
        #pragma unroll
        for (int kk = 0; kk < 16; kk++) {
            float a[4], bb[4];
            #pragma unroll
            for (int i = 0; i < 4; i++) a[i] = As[kk][ty * 4 + i];
            #pragma unroll
            for (int j = 0; j < 4; j++) bb[j] = Bs[kk][tx * 4 + j];
            #pragma unroll
            for (int i = 0; i < 4; i++)
                #pragma unroll
                for (int j = 0; j < 4; j++)
                    acc[i][j] += a[i] * bb[j];
        }
        __syncthreads();
    }
    #pragma unroll
    for (int i = 0; i < 4; i++) {
        int gr = row0 + ty * 4 + i;
        if (gr < M) {
            #pragma unroll
            for (int j = 0; j < 4; j++) {
                int gc = col0 + tx * 4 + j;
                C[gr * 256 + gc] = acc[i][j] + bias[gc];
            }
        }
    }
}

// ---------------- Edge pass layer1: wave per edge, 256 channels ----------------
__global__ __launch_bounds__(256) void edge1_kernel(const float* __restrict__ h,
                                                    const int* __restrict__ ei,
                                                    const float* __restrict__ gamma_p,
                                                    float* __restrict__ num,
                                                    float* __restrict__ denom) {
    int lane = threadIdx.x & 63;
    int e = blockIdx.x * 4 + (threadIdx.x >> 6);
    if (e >= N_EDGES) return;
    int src = ei[e];
    int dst = ei[N_EDGES + e];
    const float4* hs = (const float4*)(h + (size_t)src * 256);
    const float4* hd = (const float4*)(h + (size_t)dst * 256);
    float4 a = hs[lane];
    float4 b = hd[lane];
    float dx = a.x - b.x, dy = a.y - b.y, dz = a.z - b.z, dw = a.w - b.w;
    float d2 = dx * dx + dy * dy + dz * dz + dw * dw;
    #pragma unroll
    for (int m = 1; m < 64; m <<= 1) d2 += __shfl_xor(d2, m, 64);
    float w = __expf(-gamma_p[0] * d2);
    if (lane == 0) atomicAdd(&denom[dst], w);
    float* np = num + (size_t)dst * 256 + lane * 4;
    atomicAdd(np + 0, w * a.x);
    atomicAdd(np + 1, w * a.y);
    atomicAdd(np + 2, w * a.z);
    atomicAdd(np + 3, w * a.w);
}

// ---------------- divide + per-channel stats, C=256 (in-place) ----------------
__global__ __launch_bounds__(256) void div_stats1_kernel(float* __restrict__ x,
                                                         const float* __restrict__ denom,
                                                         float* __restrict__ sum,
                                                         float* __restrict__ sumsq) {
    int c = threadIdx.x;  // 0..255
    float s = 0.f, s2 = 0.f;
    for (int r = blockIdx.x; r < N_NODES; r += gridDim.x) {
        float v = x[(size_t)r * 256 + c] / (denom[r] + 1e-16f);
        x[(size_t)r * 256 + c] = v;
        s += v;
        s2 += v * v;
    }
    atomicAdd(&sum[c], s);
    atomicAdd(&sumsq[c], s2);
}

// ---------------- BN + ReLU, C=256 (in-place) ----------------
__global__ __launch_bounds__(256) void bnrelu1_kernel(float* __restrict__ x,
                                                      const float* __restrict__ sum,
                                                      const float* __restrict__ sumsq,
                                                      const float* __restrict__ g,
                                                      const float* __restrict__ b) {
    size_t i = (size_t)blockIdx.x * 256 + threadIdx.x;
    if (i >= (size_t)N_NODES * 256) return;
    int c = (int)(i & 255);
    const float invN = 1.f / N_NODES;
    float mu = sum[c] * invN;
    float var = sumsq[c] * invN - mu * mu;
    float v = (x[i] - mu) * rsqrtf(var + 1e-5f) * g[c] + b[c];
    x[i] = fmaxf(v, 0.f);
}

// ---------------- GEMM2: h2 = y1 @ W2 + b2   [50000,256]x[256,40] ----------------
__global__ __launch_bounds__(256) void gemm2_kernel(const float* __restrict__ X,
                                                    const float* __restrict__ W,
                                                    const float* __restrict__ bias,
                                                    float* __restrict__ H) {
    int i = blockIdx.x * 256 + threadIdx.x;
    if (i >= N_NODES * OUTC) return;
    int row = i / OUTC;
    int c = i - row * OUTC;
    const float* x = X + (size_t)row * 256;
    const float* w = W + c;
    float acc = bias[c];
    #pragma unroll 8
    for (int k = 0; k < 256; k++) acc += x[k] * w[k * OUTC];
    H[i] = acc;
}

// ---------------- Edge pass layer2: wave per edge, 40 channels ----------------
__global__ __launch_bounds__(256) void edge2_kernel(const float* __restrict__ h,
                                                    const int* __restrict__ ei,
                                                    const float* __restrict__ gamma_p,
                                                    float* __restrict__ num,
                                                    float* __restrict__ denom) {
    int lane = threadIdx.x & 63;
    int e = blockIdx.x * 4 + (threadIdx.x >> 6);
    if (e >= N_EDGES) return;
    int src = ei[e];
    int dst = ei[N_EDGES + e];
    float4 a = make_float4(0.f, 0.f, 0.f, 0.f);
    float4 b = a;
    if (lane < 10) {
        a = ((const float4*)(h + (size_t)src * OUTC))[lane];
        b = ((const float4*)(h + (size_t)dst * OUTC))[lane];
    }
    float dx = a.x - b.x, dy = a.y - b.y, dz = a.z - b.z, dw = a.w - b.w;
    float d2 = dx * dx + dy * dy + dz * dz + dw * dw;
    #pragma unroll
    for (int m = 1; m < 64; m <<= 1) d2 += __shfl_xor(d2, m, 64);
    float w = __expf(-gamma_p[0] * d2);
    if (lane == 0) atomicAdd(&denom[dst], w);
    if (lane < 10) {
        float* np = num + (size_t)dst * OUTC + lane * 4;
        atomicAdd(np + 0, w * a.x);
        atomicAdd(np + 1, w * a.y);
        atomicAdd(np + 2, w * a.z);
        atomicAdd(np + 3, w * a.w);
    }
}

// ---------------- divide + stats, C=40 (in-place) ----------------
__global__ __launch_bounds__(256) void div_stats2_kernel(float* __restrict__ x,
                                                         const float* __restrict__ denom,
                                                         float* __restrict__ sum,
                                                         float* __restrict__ sumsq) {
    int c = threadIdx.x;   // blockDim=(64,4)
    if (c >= OUTC) return;
    float s = 0.f, s2 = 0.f;
    for (int r = blockIdx.x * 4 + threadIdx.y; r < N_NODES; r += gridDim.x * 4) {
        float v = x[(size_t)r * OUTC + c] / (denom[r] + 1e-16f);
        x[(size_t)r * OUTC + c] = v;
        s += v;
        s2 += v * v;
    }
    atomicAdd(&sum[c], s);
    atomicAdd(&sumsq[c], s2);
}

// ---------------- BN2 + ReLU + gather + log_softmax ----------------
__global__ __launch_bounds__(256) void final_kernel(const float* __restrict__ x2,
                                                    const float* __restrict__ sum,
                                                    const float* __restrict__ sumsq,
                                                    const float* __restrict__ g,
                                                    const float* __restrict__ b,
                                                    const int* __restrict__ batch,
                                                    float* __restrict__ out) {
    int lane = threadIdx.x & 63;
    int row = blockIdx.x * 4 + (threadIdx.x >> 6);
    if (row >= N_BATCH) return;
    int node = batch[row];
    bool act = lane < OUTC;
    float v = -INFINITY;
    if (act) {
        const float invN = 1.f / N_NODES;
        float mu = sum[lane] * invN;
        float var = sumsq[lane] * invN - mu * mu;
        float xv = x2[(size_t)node * OUTC + lane];
        float y = (xv - mu) * rsqrtf(var + 1e-5f) * g[lane] + b[lane];
        v = fmaxf(y, 0.f);
    }
    float m = v;
    #pragma unroll
    for (int s = 1; s < 64; s <<= 1) m = fmaxf(m, __shfl_xor(m, s, 64));
    float p = act ? expf(v - m) : 0.f;
    float ssum = p;
    #pragma unroll
    for (int s = 1; s < 64; s <<= 1) ssum += __shfl_xor(ssum, s, 64);
    if (act) out[(size_t)row * OUTC + lane] = v - m - logf(ssum);
}

extern "C" void kernel_launch(void* const* d_in, const int* in_sizes, int n_in,
                              void* d_out, int out_size, void* d_ws, size_t ws_size,
                              hipStream_t stream) {
    const float* feat   = (const float*)d_in[0];
    const int*   ei     = (const int*)d_in[1];
    const int*   batch  = (const int*)d_in[2];
    const float* W1     = (const float*)d_in[3];
    const float* b1     = (const float*)d_in[4];
    const float* gamma1 = (const float*)d_in[5];
    const float* W2     = (const float*)d_in[6];
    const float* b2     = (const float*)d_in[7];
    const float* gamma2 = (const float*)d_in[8];
    const float* bn1w   = (const float*)d_in[9];
    const float* bn1b   = (const float*)d_in[10];
    const float* bn2w   = (const float*)d_in[11];
    const float* bn2b   = (const float*)d_in[12];

    char* ws = (char*)d_ws;
    // layout (aliased by liveness):
    //   [0, 51.2MB)      h1  (later h2)
    //   [51.2, 102.4MB)  num1 -> x1 -> y1 (later num2 -> x2)
    //   [102.4MB, +200KB) denom1 (later denom2)
    //   [102.6MB, +4KB)  sum1[256] sumsq1[256] sum2[64] sumsq2[64]
    float* h1     = (float*)ws;
    float* num1   = (float*)(ws + 51200000);
    float* denom1 = (float*)(ws + 102400000);
    float* stats  = (float*)(ws + 102600192);
    float* sum1   = stats;
    float* sumsq1 = stats + 256;
    float* sum2   = stats + 512;
    float* sumsq2 = stats + 576;
    float* h2     = h1;
    float* num2   = num1;
    float* denom2 = denom1;
    float* out    = (float*)d_out;

    // layer 1
    gemm1_kernel<<<dim3((N_NODES + 63) / 64, 4), 256, 0, stream>>>(feat, W1, b1, h1, N_NODES);
    hipMemsetAsync(num1, 0, (size_t)N_NODES * 256 * 4, stream);
    hipMemsetAsync(denom1, 0, (size_t)N_NODES * 4, stream);
    hipMemsetAsync(stats, 0, 4096, stream);
    edge1_kernel<<<N_EDGES / 4, 256, 0, stream>>>(h1, ei, gamma1, num1, denom1);
    div_stats1_kernel<<<512, 256, 0, stream>>>(num1, denom1, sum1, sumsq1);
    bnrelu1_kernel<<<(N_NODES * 256 + 255) / 256, 256, 0, stream>>>(num1, sum1, sumsq1, bn1w, bn1b);

    // layer 2
    gemm2_kernel<<<(N_NODES * OUTC + 255) / 256, 256, 0, stream>>>(num1, W2, b2, h2);
    hipMemsetAsync(num2, 0, (size_t)N_NODES * OUTC * 4, stream);
    hipMemsetAsync(denom2, 0, (size_t)N_NODES * 4, stream);
    edge2_kernel<<<N_EDGES / 4, 256, 0, stream>>>(h2, ei, gamma2, num2, denom2);
    div_stats2_kernel<<<512, dim3(64, 4), 0, stream>>>(num2, denom2, sum2, sumsq2);
    final_kernel<<<(N_BATCH + 3) / 4, 256, 0, stream>>>(num2, sum2, sumsq2, bn2w, bn2b, batch, out);
}

// Round 2
// 872.339 us; speedup vs baseline: 4.3197x; 4.3197x over previous
//
#include <hip/hip_runtime.h>
#include <hip/hip_bf16.h>
#include <math.h>

#define N_NODES 50000
#define N_EDGES 800000
#define FEAT 256
#define HID 256
#define OUTC 40
#define N_BATCH 10000

// ---------------- GEMM1: h1 = feat @ W1 + b1   [50000,256]x[256,256] ----------------
__global__ __launch_bounds__(256) void gemm1_kernel(const float* __restrict__ A,
                                                    const float* __restrict__ B,
                                                    const float* __restrict__ bias,
                                                    float* __restrict__ C, int M) {
    __shared__ float As[16][65];
    __shared__ float Bs[16][65];
    int tx = threadIdx.x & 15;
    int ty = threadIdx.x >> 4;
    int row0 = blockIdx.x * 64;
    int col0 = blockIdx.y * 64;
    float acc[4][4] = {};
    for (int k0 = 0; k0 < 256; k0 += 16) {
        #pragma unroll
        for (int i = 0; i < 4; i++) {
            int idx = threadIdx.x + i * 256;   // 0..1023
            int r = idx >> 4;                  // 0..63 row in tile
            int kk = idx & 15;                 // k in tile
            int gr = row0 + r;
            As[kk][r] = (gr < M) ? A[gr * 256 + k0 + kk] : 0.f;
        }
        #pragma unroll
        for (int i = 0; i < 4; i++) {
            int idx = threadIdx.x + i * 256;
            int r = idx >> 6;                  // k 0..15
            int cc = idx & 63;                 // col 0..63
            Bs[r][cc] = B[(k0 + r) * 256 + col0 + cc];
        }
        __syncthreads();
        #pragma unroll
        for (int kk = 0; kk < 16; kk++) {
            float a[4], bb[4];
            #pragma unroll
            for (int i = 0; i < 4; i++) a[i] = As[kk][ty * 4 + i];
            #pragma unroll
            for (int j = 0; j < 4; j++) bb[j] = Bs[kk][tx * 4 + j];
            #pragma unroll
            for (int i = 0; i < 4; i++)
                #pragma unroll
                for (int j = 0; j < 4; j++)
                    acc[i][j] += a[i] * bb[j];
        }
        __syncthreads();
    }
    #pragma unroll
    for (int i = 0; i < 4; i++) {
        int gr = row0 + ty * 4 + i;
        if (gr < M) {
            #pragma unroll
            for (int j = 0; j < 4; j++) {
                int gc = col0 + tx * 4 + j;
                C[gr * 256 + gc] = acc[i][j] + bias[gc];
            }
        }
    }
}

// ---------------- CSR build: histogram / scan / scatter ----------------
__global__ __launch_bounds__(256) void hist_kernel(const int* __restrict__ ei,
                                                   int* __restrict__ cnt) {
    int e = blockIdx.x * 256 + threadIdx.x;
    if (e < N_EDGES) atomicAdd(&cnt[ei[N_EDGES + e]], 1);
}

__global__ __launch_bounds__(1024) void scan_kernel(const int* __restrict__ cnt,
                                                    int* __restrict__ offs) {
    __shared__ int sdata[1024];
    int t = threadIdx.x;
    const int CH = (N_NODES + 1023) / 1024;  // 49
    int base = t * CH;
    int s = 0;
    for (int i = 0; i < CH; i++) {
        int idx = base + i;
        if (idx < N_NODES) s += cnt[idx];
    }
    sdata[t] = s;
    __syncthreads();
    for (int off = 1; off < 1024; off <<= 1) {
        int v = (t >= off) ? sdata[t - off] : 0;
        __syncthreads();
        sdata[t] += v;
        __syncthreads();
    }
    int run = (t > 0) ? sdata[t - 1] : 0;
    for (int i = 0; i < CH; i++) {
        int idx = base + i;
        if (idx < N_NODES) {
            offs[idx] = run;
            run += cnt[idx];
        }
    }
    if (t == 1023) offs[N_NODES] = sdata[1023];
}

__global__ __launch_bounds__(256) void scatter_kernel(const int* __restrict__ ei,
                                                      const int* __restrict__ offs,
                                                      int* __restrict__ cur,
                                                      int* __restrict__ srcs) {
    int e = blockIdx.x * 256 + threadIdx.x;
    if (e >= N_EDGES) return;
    int d = ei[N_EDGES + e];
    int pos = offs[d] + atomicAdd(&cur[d], 1);
    srcs[pos] = ei[e];
}

// ---------------- Aggregation layer1: wave per dst node, 256 channels ----------------
__global__ __launch_bounds__(256) void agg1_kernel(const float* __restrict__ h,
                                                   const int* __restrict__ offs,
                                                   const int* __restrict__ srcs,
                                                   const float* __restrict__ gamma_p,
                                                   float* __restrict__ x1) {
    int lane = threadIdx.x & 63;
    int node = blockIdx.x * 4 + (threadIdx.x >> 6);
    if (node >= N_NODES) return;
    float g = gamma_p[0];
    float4 hd = ((const float4*)(h + (size_t)node * 256))[lane];
    int beg = offs[node], end = offs[node + 1];
    float4 acc = make_float4(0.f, 0.f, 0.f, 0.f);
    float den = 0.f;
    for (int i = beg; i < end; i++) {
        int s = srcs[i];
        float4 a = ((const float4*)(h + (size_t)s * 256))[lane];
        float dx = a.x - hd.x, dy = a.y - hd.y, dz = a.z - hd.z, dw = a.w - hd.w;
        float d2 = dx * dx + dy * dy + dz * dz + dw * dw;
        #pragma unroll
        for (int m = 1; m < 64; m <<= 1) d2 += __shfl_xor(d2, m, 64);
        float w = __expf(-g * d2);
        den += w;
        acc.x += w * a.x; acc.y += w * a.y; acc.z += w * a.z; acc.w += w * a.w;
    }
    float inv = 1.f / (den + 1e-16f);
    acc.x *= inv; acc.y *= inv; acc.z *= inv; acc.w *= inv;
    ((float4*)(x1 + (size_t)node * 256))[lane] = acc;
}

// ---------------- per-channel stats, C=256 ----------------
__global__ __launch_bounds__(256) void stats1_kernel(const float* __restrict__ x,
                                                     float* __restrict__ sum,
                                                     float* __restrict__ sumsq) {
    int c = threadIdx.x;  // 0..255
    float s = 0.f, s2 = 0.f;
    for (int r = blockIdx.x; r < N_NODES; r += gridDim.x) {
        float v = x[(size_t)r * 256 + c];
        s += v;
        s2 += v * v;
    }
    atomicAdd(&sum[c], s);
    atomicAdd(&sumsq[c], s2);
}

// ---------------- BN + ReLU, C=256 (in-place) ----------------
__global__ __launch_bounds__(256) void bnrelu1_kernel(float* __restrict__ x,
                                                      const float* __restrict__ sum,
                                                      const float* __restrict__ sumsq,
                                                      const float* __restrict__ g,
                                                      const float* __restrict__ b) {
    size_t i = (size_t)blockIdx.x * 256 + threadIdx.x;
    if (i >= (size_t)N_NODES * 256) return;
    int c = (int)(i & 255);
    const float invN = 1.f / N_NODES;
    float mu = sum[c] * invN;
    float var = sumsq[c] * invN - mu * mu;
    float v = (x[i] - mu) * rsqrtf(var + 1e-5f) * g[c] + b[c];
    x[i] = fmaxf(v, 0.f);
}

// ---------------- GEMM2: h2 = y1 @ W2 + b2   [50000,256]x[256,40] ----------------
__global__ __launch_bounds__(256) void gemm2_kernel(const float* __restrict__ X,
                                                    const float* __restrict__ W,
                                                    const float* __restrict__ bias,
                                                    float* __restrict__ H) {
    int i = blockIdx.x * 256 + threadIdx.x;
    if (i >= N_NODES * OUTC) return;
    int row = i / OUTC;
    int c = i - row * OUTC;
    const float* x = X + (size_t)row * 256;
    const float* w = W + c;
    float acc = bias[c];
    #pragma unroll 8
    for (int k = 0; k < 256; k++) acc += x[k] * w[k * OUTC];
    H[i] = acc;
}

// ---------------- Aggregation layer2: wave per dst node, 40 channels ----------------
__global__ __launch_bounds__(256) void agg2_kernel(const float* __restrict__ h,
                                                   const int* __restrict__ offs,
                                                   const int* __restrict__ srcs,
                                                   const float* __restrict__ gamma_p,
                                                   float* __restrict__ x2) {
    int lane = threadIdx.x & 63;
    int node = blockIdx.x * 4 + (threadIdx.x >> 6);
    if (node >= N_NODES) return;
    float g = gamma_p[0];
    bool act = lane < OUTC;
    float hd = act ? h[(size_t)node * OUTC + lane] : 0.f;
    int beg = offs[node], end = offs[node + 1];
    float acc = 0.f, den = 0.f;
    for (int i = beg; i < end; i++) {
        int s = srcs[i];
        float a = act ? h[(size_t)s * OUTC + lane] : 0.f;
        float d = a - hd;
        float d2 = d * d;
        #pragma unroll
        for (int m = 1; m < 64; m <<= 1) d2 += __shfl_xor(d2, m, 64);
        float w = __expf(-g * d2);
        den += w;
        acc += w * a;
    }
    if (act) x2[(size_t)node * OUTC + lane] = acc / (den + 1e-16f);
}

// ---------------- per-channel stats, C=40 ----------------
__global__ __launch_bounds__(256) void stats2_kernel(const float* __restrict__ x,
                                                     float* __restrict__ sum,
                                                     float* __restrict__ sumsq) {
    int c = threadIdx.x;   // blockDim=(64,4)
    if (c >= OUTC) return;
    float s = 0.f, s2 = 0.f;
    for (int r = blockIdx.x * 4 + threadIdx.y; r < N_NODES; r += gridDim.x * 4) {
        float v = x[(size_t)r * OUTC + c];
        s += v;
        s2 += v * v;
    }
    atomicAdd(&sum[c], s);
    atomicAdd(&sumsq[c], s2);
}

// ---------------- BN2 + ReLU + gather + log_softmax ----------------
__global__ __launch_bounds__(256) void final_kernel(const float* __restrict__ x2,
                                                    const float* __restrict__ sum,
                                                    const float* __restrict__ sumsq,
                                                    const float* __restrict__ g,
                                                    const float* __restrict__ b,
                                                    const int* __restrict__ batch,
                                                    float* __restrict__ out) {
    int lane = threadIdx.x & 63;
    int row = blockIdx.x * 4 + (threadIdx.x >> 6);
    if (row >= N_BATCH) return;
    int node = batch[row];
    bool act = lane < OUTC;
    float v = -INFINITY;
    if (act) {
        const float invN = 1.f / N_NODES;
        float mu = sum[lane] * invN;
        float var = sumsq[lane] * invN - mu * mu;
        float xv = x2[(size_t)node * OUTC + lane];
        float y = (xv - mu) * rsqrtf(var + 1e-5f) * g[lane] + b[lane];
        v = fmaxf(y, 0.f);
    }
    float m = v;
    #pragma unroll
    for (int s = 1; s < 64; s <<= 1) m = fmaxf(m, __shfl_xor(m, s, 64));
    float p = act ? expf(v - m) : 0.f;
    float ssum = p;
    #pragma unroll
    for (int s = 1; s < 64; s <<= 1) ssum += __shfl_xor(ssum, s, 64);
    if (act) out[(size_t)row * OUTC + lane] = v - m - logf(ssum);
}

extern "C" void kernel_launch(void* const* d_in, const int* in_sizes, int n_in,
                              void* d_out, int out_size, void* d_ws, size_t ws_size,
                              hipStream_t stream) {
    const float* feat   = (const float*)d_in[0];
    const int*   ei     = (const int*)d_in[1];
    const int*   batch  = (const int*)d_in[2];
    const float* W1     = (const float*)d_in[3];
    const float* b1     = (const float*)d_in[4];
    const float* gamma1 = (const float*)d_in[5];
    const float* W2     = (const float*)d_in[6];
    const float* b2     = (const float*)d_in[7];
    const float* gamma2 = (const float*)d_in[8];
    const float* bn1w   = (const float*)d_in[9];
    const float* bn1b   = (const float*)d_in[10];
    const float* bn2w   = (const float*)d_in[11];
    const float* bn2b   = (const float*)d_in[12];

    char* ws = (char*)d_ws;
    // layout (aliased by liveness):
    //   [0, 51.2MB)        h1  (later h2 = [50000,40])
    //   [51.2, 102.4MB)    x1  (later x2 = [50000,40])
    //   [102.4MB, +200KB)  offs[50001]
    //   [+200KB]           cnt[50000]
    //   [+200KB]           cur[50000]
    //   [+3.2MB]           srcs[800000]
    //   [+4KB]             sum1[256] sumsq1[256] sum2[64] sumsq2[64]
    float* h1    = (float*)ws;
    float* x1    = (float*)(ws + 51200000);
    int*   offs  = (int*)(ws + 102400000);
    int*   cnt   = (int*)(ws + 102400000 + 200064);
    int*   cur   = (int*)(ws + 102400000 + 400128);
    int*   srcs  = (int*)(ws + 102400000 + 600192);
    float* stats = (float*)(ws + 102400000 + 3800256);
    float* sum1   = stats;
    float* sumsq1 = stats + 256;
    float* sum2   = stats + 512;
    float* sumsq2 = stats + 576;
    float* h2 = h1;
    float* x2 = x1;
    float* out = (float*)d_out;

    // CSR build (shared by both layers) — overlapped with gemm1 in issue order
    hipMemsetAsync(cnt, 0, N_NODES * 4, stream);
    hipMemsetAsync(cur, 0, N_NODES * 4, stream);
    hipMemsetAsync(stats, 0, 4096, stream);
    hist_kernel<<<(N_EDGES + 255) / 256, 256, 0, stream>>>(ei, cnt);
    scan_kernel<<<1, 1024, 0, stream>>>(cnt, offs);
    scatter_kernel<<<(N_EDGES + 255) / 256, 256, 0, stream>>>(ei, offs, cur, srcs);

    // layer 1
    gemm1_kernel<<<dim3((N_NODES + 63) / 64, 4), 256, 0, stream>>>(feat, W1, b1, h1, N_NODES);
    agg1_kernel<<<(N_NODES + 3) / 4, 256, 0, stream>>>(h1, offs, srcs, gamma1, x1);
    stats1_kernel<<<512, 256, 0, stream>>>(x1, sum1, sumsq1);
    bnrelu1_kernel<<<(N_NODES * 256 + 255) / 256, 256, 0, stream>>>(x1, sum1, sumsq1, bn1w, bn1b);

    // layer 2
    gemm2_kernel<<<(N_NODES * OUTC + 255) / 256, 256, 0, stream>>>(x1, W2, b2, h2);
    agg2_kernel<<<(N_NODES + 3) / 4, 256, 0, stream>>>(h2, offs, srcs, gamma2, x2);
    stats2_kernel<<<512, dim3(64, 4), 0, stream>>>(x2, sum2, sumsq2);
    final_kernel<<<(N_BATCH + 3) / 4, 256, 0, stream>>>(x2, sum2, sumsq2, bn2w, bn2b, batch, out);
}

// Round 3
// 632.904 us; speedup vs baseline: 5.9539x; 1.3783x over previous
//
#include <hip/hip_runtime.h>
#include <math.h>

#define N_NODES 50000
#define N_EDGES 800000
#define OUTC 40
#define N_BATCH 10000

typedef float f32x4 __attribute__((ext_vector_type(4)));
typedef short s16x8 __attribute__((ext_vector_type(8)));
typedef short s16x4 __attribute__((ext_vector_type(4)));

union Frag { s16x8 v; s16x4 h[2]; };

__device__ inline unsigned short f2bf(float f) {
    unsigned int u = __float_as_uint(f);
    u += 0x7fff + ((u >> 16) & 1);           // round-to-nearest-even
    return (unsigned short)(u >> 16);
}
__device__ inline float4 bfq(uint2 u) {      // 4 packed bf16 -> float4
    float4 r;
    r.x = __uint_as_float(u.x << 16);
    r.y = __uint_as_float(u.x & 0xffff0000u);
    r.z = __uint_as_float(u.y << 16);
    r.w = __uint_as_float(u.y & 0xffff0000u);
    return r;
}

// ---------------- W1 [256k][256n] fp32 -> W1T bf16 [256n][256k] ----------------
__global__ __launch_bounds__(256) void w1t_kernel(const float* __restrict__ W1,
                                                  unsigned short* __restrict__ W1T) {
    int k = blockIdx.x;           // row of W1 (coalesced read)
    int n = threadIdx.x;
    W1T[(size_t)n * 256 + k] = f2bf(W1[(size_t)k * 256 + n]);
}

// ---------------- GEMM1 MFMA: h1 = bf16(feat @ W1 + b1), output bf16 ----------------
// 128x128 tile, BK=32, 4 waves; A row-major fp32->bf16 staged, B from W1T (n-major)
#define LDA 40  // ushort stride: 32 k + 8 pad (2-way bank aliasing only)
__global__ __launch_bounds__(256) void gemm1_mfma(const float* __restrict__ A,
                                                  const unsigned short* __restrict__ BT,
                                                  const float* __restrict__ bias,
                                                  unsigned short* __restrict__ C) {
    __shared__ unsigned short As[128 * LDA];
    __shared__ unsigned short Bs[128 * LDA];
    int t = threadIdx.x;
    int lane = t & 63, wave = t >> 6;
    int ln = lane & 15, quad = lane >> 4;
    int row0 = blockIdx.x * 128;
    int col0 = blockIdx.y * 128;
    int m0 = (wave & 1) * 64, n0 = (wave >> 1) * 64;
    f32x4 acc[4][4];
    #pragma unroll
    for (int i = 0; i < 4; i++)
        #pragma unroll
        for (int j = 0; j < 4; j++) acc[i][j] = (f32x4){0.f, 0.f, 0.f, 0.f};
    int r = t >> 1, half = t & 1;

    for (int k0 = 0; k0 < 256; k0 += 32) {
        {   // stage A: 16 fp32 -> 16 bf16 per thread
            int gr = row0 + r;
            float4 v[4];
            if (gr < N_NODES) {
                const float4* src = (const float4*)(A + (size_t)gr * 256 + k0 + half * 16);
                v[0] = src[0]; v[1] = src[1]; v[2] = src[2]; v[3] = src[3];
            } else {
                float4 z = make_float4(0.f, 0.f, 0.f, 0.f);
                v[0] = z; v[1] = z; v[2] = z; v[3] = z;
            }
            ushort4* dst = (ushort4*)&As[r * LDA + half * 16];
            #pragma unroll
            for (int q = 0; q < 4; q++) {
                ushort4 u;
                u.x = f2bf(v[q].x); u.y = f2bf(v[q].y);
                u.z = f2bf(v[q].z); u.w = f2bf(v[q].w);
                dst[q] = u;
            }
        }
        {   // stage B: 16 bf16 per thread from W1T row (col0+r)
            const ushort4* src = (const ushort4*)(BT + (size_t)(col0 + r) * 256 + k0 + half * 16);
            ushort4* dst = (ushort4*)&Bs[r * LDA + half * 16];
            dst[0] = src[0]; dst[1] = src[1]; dst[2] = src[2]; dst[3] = src[3];
        }
        __syncthreads();
        Frag af[4], bf[4];
        #pragma unroll
        for (int i = 0; i < 4; i++) {
            int ar = m0 + i * 16 + ln;
            af[i].h[0] = *(const s16x4*)&As[ar * LDA + quad * 8];
            af[i].h[1] = *(const s16x4*)&As[ar * LDA + quad * 8 + 4];
            int br = n0 + i * 16 + ln;
            bf[i].h[0] = *(const s16x4*)&Bs[br * LDA + quad * 8];
            bf[i].h[1] = *(const s16x4*)&Bs[br * LDA + quad * 8 + 4];
        }
        #pragma unroll
        for (int i = 0; i < 4; i++)
            #pragma unroll
            for (int j = 0; j < 4; j++)
                acc[i][j] = __builtin_amdgcn_mfma_f32_16x16x32_bf16(af[i].v, bf[j].v, acc[i][j], 0, 0, 0);
        __syncthreads();
    }
    // epilogue: D row = quad*4+reg, col = lane&15
    #pragma unroll
    for (int j = 0; j < 4; j++) {
        int gc = col0 + n0 + j * 16 + ln;
        float bv = bias[gc];
        #pragma unroll
        for (int i = 0; i < 4; i++) {
            int gb = row0 + m0 + i * 16 + quad * 4;
            #pragma unroll
            for (int rg = 0; rg < 4; rg++) {
                int gr = gb + rg;
                if (gr < N_NODES) C[(size_t)gr * 256 + gc] = f2bf(acc[i][j][rg] + bv);
            }
        }
    }
}

// ---------------- CSR build ----------------
__global__ __launch_bounds__(256) void hist_kernel(const int* __restrict__ ei,
                                                   int* __restrict__ cnt) {
    int e = blockIdx.x * 256 + threadIdx.x;
    if (e < N_EDGES) atomicAdd(&cnt[ei[N_EDGES + e]], 1);
}

__global__ __launch_bounds__(1024) void scan_kernel(const int* __restrict__ cnt,
                                                    int* __restrict__ offs) {
    __shared__ int sdata[1024];
    int t = threadIdx.x;
    const int CH = (N_NODES + 1023) / 1024;
    int base = t * CH;
    int s = 0;
    for (int i = 0; i < CH; i++) {
        int idx = base + i;
        if (idx < N_NODES) s += cnt[idx];
    }
    sdata[t] = s;
    __syncthreads();
    for (int off = 1; off < 1024; off <<= 1) {
        int v = (t >= off) ? sdata[t - off] : 0;
        __syncthreads();
        sdata[t] += v;
        __syncthreads();
    }
    int run = (t > 0) ? sdata[t - 1] : 0;
    for (int i = 0; i < CH; i++) {
        int idx = base + i;
        if (idx < N_NODES) {
            offs[idx] = run;
            run += cnt[idx];
        }
    }
    if (t == 1023) offs[N_NODES] = sdata[1023];
}

__global__ __launch_bounds__(256) void scatter_kernel(const int* __restrict__ ei,
                                                      const int* __restrict__ offs,
                                                      int* __restrict__ cur,
                                                      int* __restrict__ srcs) {
    int e = blockIdx.x * 256 + threadIdx.x;
    if (e >= N_EDGES) return;
    int d = ei[N_EDGES + e];
    int pos = offs[d] + atomicAdd(&cur[d], 1);
    srcs[pos] = ei[e];
}

// ---------------- agg1: wave per dst node, h1 in bf16 ----------------
__global__ __launch_bounds__(256) void agg1_kernel(const unsigned short* __restrict__ h,
                                                   const int* __restrict__ offs,
                                                   const int* __restrict__ srcs,
                                                   const float* __restrict__ gamma_p,
                                                   float* __restrict__ x1) {
    int lane = threadIdx.x & 63;
    int node = blockIdx.x * 4 + (threadIdx.x >> 6);
    if (node >= N_NODES) return;
    float g = gamma_p[0];
    float4 hd = bfq(((const uint2*)(h + (size_t)node * 256))[lane]);
    int beg = offs[node], end = offs[node + 1];
    float4 acc = make_float4(0.f, 0.f, 0.f, 0.f);
    float den = 0.f;
    for (int i = beg; i < end; i++) {
        int s = srcs[i];
        float4 a = bfq(((const uint2*)(h + (size_t)s * 256))[lane]);
        float dx = a.x - hd.x, dy = a.y - hd.y, dz = a.z - hd.z, dw = a.w - hd.w;
        float d2 = dx * dx + dy * dy + dz * dz + dw * dw;
        #pragma unroll
        for (int m = 1; m < 64; m <<= 1) d2 += __shfl_xor(d2, m, 64);
        float w = __expf(-g * d2);
        den += w;
        acc.x += w * a.x; acc.y += w * a.y; acc.z += w * a.z; acc.w += w * a.w;
    }
    float inv = 1.f / (den + 1e-16f);
    acc.x *= inv; acc.y *= inv; acc.z *= inv; acc.w *= inv;
    ((float4*)(x1 + (size_t)node * 256))[lane] = acc;
}

// ---------------- per-channel stats, C=256 ----------------
__global__ __launch_bounds__(256) void stats1_kernel(const float* __restrict__ x,
                                                     float* __restrict__ sum,
                                                     float* __restrict__ sumsq) {
    int c = threadIdx.x;
    float s = 0.f, s2 = 0.f;
    for (int r = blockIdx.x; r < N_NODES; r += gridDim.x) {
        float v = x[(size_t)r * 256 + c];
        s += v;
        s2 += v * v;
    }
    atomicAdd(&sum[c], s);
    atomicAdd(&sumsq[c], s2);
}

// ---------------- GEMM2 with fused BN1+ReLU: h2 = relu(bn(x1)) @ W2 + b2 ----------------
// block=256: 64 row-slots x 4 cgroups; 4 rows per slot (stride 64) -> 256 rows/block
__global__ __launch_bounds__(256) void gemm2_kernel(const float* __restrict__ X,
                                                    const float* __restrict__ W2,
                                                    const float* __restrict__ bias,
                                                    const float* __restrict__ sum1,
                                                    const float* __restrict__ sumsq1,
                                                    const float* __restrict__ bg,
                                                    const float* __restrict__ bb,
                                                    float* __restrict__ H) {
    __shared__ float W2s[40 * 260];
    __shared__ float aas[256], bbs[256];
    int t = threadIdx.x;
    for (int c = 0; c < 40; c++) W2s[c * 260 + t] = W2[(size_t)t * 40 + c];
    {
        const float invN = 1.f / N_NODES;
        float mu = sum1[t] * invN;
        float var = sumsq1[t] * invN - mu * mu;
        float rs = rsqrtf(var + 1e-5f) * bg[t];
        aas[t] = rs;
        bbs[t] = bb[t] - mu * rs;
    }
    __syncthreads();
    int slot = t >> 2, cg = t & 3;
    int rbase = blockIdx.x * 256 + slot;
    const float4* xp[4];
    #pragma unroll
    for (int rr = 0; rr < 4; rr++) xp[rr] = (const float4*)(X + (size_t)(rbase + rr * 64) * 256);
    float acc[4][10];
    #pragma unroll
    for (int rr = 0; rr < 4; rr++)
        #pragma unroll
        for (int i = 0; i < 10; i++) acc[rr][i] = 0.f;

    for (int k4 = 0; k4 < 64; k4++) {
        int k = k4 * 4;
        float4 a4 = *(const float4*)&aas[k];
        float4 b4 = *(const float4*)&bbs[k];
        float4 w4[10];
        #pragma unroll
        for (int i = 0; i < 10; i++) w4[i] = *(const float4*)&W2s[(cg * 10 + i) * 260 + k];
        #pragma unroll
        for (int rr = 0; rr < 4; rr++) {
            float4 xv = xp[rr][k4];   // OOB rows read inside ws (safe), stores guarded
            float y0 = fmaxf(fmaf(xv.x, a4.x, b4.x), 0.f);
            float y1 = fmaxf(fmaf(xv.y, a4.y, b4.y), 0.f);
            float y2 = fmaxf(fmaf(xv.z, a4.z, b4.z), 0.f);
            float y3 = fmaxf(fmaf(xv.w, a4.w, b4.w), 0.f);
            #pragma unroll
            for (int i = 0; i < 10; i++)
                acc[rr][i] += y0 * w4[i].x + y1 * w4[i].y + y2 * w4[i].z + y3 * w4[i].w;
        }
    }
    #pragma unroll
    for (int rr = 0; rr < 4; rr++) {
        int row = rbase + rr * 64;
        if (row < N_NODES) {
            float* out = H + (size_t)row * 40 + cg * 10;
            #pragma unroll
            for (int i = 0; i < 10; i++) out[i] = acc[rr][i] + bias[cg * 10 + i];
        }
    }
}

// ---------------- agg2: wave per dst node, 40 channels ----------------
__global__ __launch_bounds__(256) void agg2_kernel(const float* __restrict__ h,
                                                   const int* __restrict__ offs,
                                                   const int* __restrict__ srcs,
                                                   const float* __restrict__ gamma_p,
                                                   float* __restrict__ x2) {
    int lane = threadIdx.x & 63;
    int node = blockIdx.x * 4 + (threadIdx.x >> 6);
    if (node >= N_NODES) return;
    float g = gamma_p[0];
    bool act = lane < OUTC;
    float hd = act ? h[(size_t)node * OUTC + lane] : 0.f;
    int beg = offs[node], end = offs[node + 1];
    float acc = 0.f, den = 0.f;
    for (int i = beg; i < end; i++) {
        int s = srcs[i];
        float a = act ? h[(size_t)s * OUTC + lane] : 0.f;
        float d = a - hd;
        float d2 = d * d;
        #pragma unroll
        for (int m = 1; m < 64; m <<= 1) d2 += __shfl_xor(d2, m, 64);
        float w = __expf(-g * d2);
        den += w;
        acc += w * a;
    }
    if (act) x2[(size_t)node * OUTC + lane] = acc / (den + 1e-16f);
}

// ---------------- per-channel stats, C=40 ----------------
__global__ __launch_bounds__(256) void stats2_kernel(const float* __restrict__ x,
                                                     float* __restrict__ sum,
                                                     float* __restrict__ sumsq) {
    int c = threadIdx.x;
    if (c >= OUTC) return;
    float s = 0.f, s2 = 0.f;
    for (int r = blockIdx.x * 4 + threadIdx.y; r < N_NODES; r += gridDim.x * 4) {
        float v = x[(size_t)r * OUTC + c];
        s += v;
        s2 += v * v;
    }
    atomicAdd(&sum[c], s);
    atomicAdd(&sumsq[c], s2);
}

// ---------------- BN2 + ReLU + gather + log_softmax ----------------
__global__ __launch_bounds__(256) void final_kernel(const float* __restrict__ x2,
                                                    const float* __restrict__ sum,
                                                    const float* __restrict__ sumsq,
                                                    const float* __restrict__ g,
                                                    const float* __restrict__ b,
                                                    const int* __restrict__ batch,
                                                    float* __restrict__ out) {
    int lane = threadIdx.x & 63;
    int row = blockIdx.x * 4 + (threadIdx.x >> 6);
    if (row >= N_BATCH) return;
    int node = batch[row];
    bool act = lane < OUTC;
    float v = -INFINITY;
    if (act) {
        const float invN = 1.f / N_NODES;
        float mu = sum[lane] * invN;
        float var = sumsq[lane] * invN - mu * mu;
        float xv = x2[(size_t)node * OUTC + lane];
        float y = (xv - mu) * rsqrtf(var + 1e-5f) * g[lane] + b[lane];
        v = fmaxf(y, 0.f);
    }
    float m = v;
    #pragma unroll
    for (int s = 1; s < 64; s <<= 1) m = fmaxf(m, __shfl_xor(m, s, 64));
    float p = act ? expf(v - m) : 0.f;
    float ssum = p;
    #pragma unroll
    for (int s = 1; s < 64; s <<= 1) ssum += __shfl_xor(ssum, s, 64);
    if (act) out[(size_t)row * OUTC + lane] = v - m - logf(ssum);
}

extern "C" void kernel_launch(void* const* d_in, const int* in_sizes, int n_in,
                              void* d_out, int out_size, void* d_ws, size_t ws_size,
                              hipStream_t stream) {
    const float* feat   = (const float*)d_in[0];
    const int*   ei     = (const int*)d_in[1];
    const int*   batch  = (const int*)d_in[2];
    const float* W1     = (const float*)d_in[3];
    const float* b1     = (const float*)d_in[4];
    const float* gamma1 = (const float*)d_in[5];
    const float* W2     = (const float*)d_in[6];
    const float* b2     = (const float*)d_in[7];
    const float* gamma2 = (const float*)d_in[8];
    const float* bn1w   = (const float*)d_in[9];
    const float* bn1b   = (const float*)d_in[10];
    const float* bn2w   = (const float*)d_in[11];
    const float* bn2b   = (const float*)d_in[12];

    char* ws = (char*)d_ws;
    // layout (aliased by liveness):
    //   [0, 25.6MB)      h1 bf16 [50000,256]   (later h2 fp32 [50000,40] = 8MB)
    //   [25.6, 76.8MB)   x1 fp32 [50000,256]   (later x2 fp32 [50000,40])
    //   [76.8MB, +128KB) W1T bf16 [256,256]
    //   [77.0MB ..)      offs / cnt / cur / srcs / stats
    unsigned short* h1  = (unsigned short*)ws;
    float* x1           = (float*)(ws + 25600000);
    unsigned short* w1t = (unsigned short*)(ws + 76800000);
    int* offs           = (int*)(ws + 77000000);
    int* cnt            = (int*)(ws + 77200064);
    int* cur            = (int*)(ws + 77400128);
    int* srcs           = (int*)(ws + 77600192);
    float* stats        = (float*)(ws + 80800256);
    float* sum1   = stats;
    float* sumsq1 = stats + 256;
    float* sum2   = stats + 512;
    float* sumsq2 = stats + 576;
    float* h2 = (float*)ws;
    float* x2 = x1;
    float* out = (float*)d_out;

    hipMemsetAsync(cnt, 0, N_NODES * 4, stream);
    hipMemsetAsync(cur, 0, N_NODES * 4, stream);
    hipMemsetAsync(stats, 0, 4096, stream);

    w1t_kernel<<<256, 256, 0, stream>>>(W1, w1t);
    hist_kernel<<<(N_EDGES + 255) / 256, 256, 0, stream>>>(ei, cnt);
    scan_kernel<<<1, 1024, 0, stream>>>(cnt, offs);
    scatter_kernel<<<(N_EDGES + 255) / 256, 256, 0, stream>>>(ei, offs, cur, srcs);

    // layer 1
    gemm1_mfma<<<dim3(391, 2), 256, 0, stream>>>(feat, w1t, b1, h1);
    agg1_kernel<<<(N_NODES + 3) / 4, 256, 0, stream>>>(h1, offs, srcs, gamma1, x1);
    stats1_kernel<<<512, 256, 0, stream>>>(x1, sum1, sumsq1);

    // layer 2 (BN1+ReLU fused into gemm2 load path)
    gemm2_kernel<<<196, 256, 0, stream>>>(x1, W2, b2, sum1, sumsq1, bn1w, bn1b, h2);
    agg2_kernel<<<(N_NODES + 3) / 4, 256, 0, stream>>>(h2, offs, srcs, gamma2, x2);
    stats2_kernel<<<512, dim3(64, 4), 0, stream>>>(x2, sum2, sumsq2);
    final_kernel<<<(N_BATCH + 3) / 4, 256, 0, stream>>>(x2, sum2, sumsq2, bn2w, bn2b, batch, out);
}

// Round 4
// 533.417 us; speedup vs baseline: 7.0643x; 1.1865x over previous
//
#include <hip/hip_runtime.h>
#include <math.h>

#define N_NODES 50000
#define N_EDGES 800000
#define OUTC 40
#define N_BATCH 10000
#define H2S 48   // padded stride for h2

typedef float f32x4 __attribute__((ext_vector_type(4)));
typedef short s16x8 __attribute__((ext_vector_type(8)));
typedef short s16x4 __attribute__((ext_vector_type(4)));

union Frag { s16x8 v; s16x4 h[2]; };

__device__ inline unsigned short f2bf(float f) {
    unsigned int u = __float_as_uint(f);
    u += 0x7fff + ((u >> 16) & 1);           // round-to-nearest-even
    return (unsigned short)(u >> 16);
}
__device__ inline void unpk8(uint4 u, float* f) {   // 8 packed bf16 -> 8 fp32
    f[0] = __uint_as_float(u.x << 16); f[1] = __uint_as_float(u.x & 0xffff0000u);
    f[2] = __uint_as_float(u.y << 16); f[3] = __uint_as_float(u.y & 0xffff0000u);
    f[4] = __uint_as_float(u.z << 16); f[5] = __uint_as_float(u.z & 0xffff0000u);
    f[6] = __uint_as_float(u.w << 16); f[7] = __uint_as_float(u.w & 0xffff0000u);
}

// ---------------- W1 [256k][256n] fp32 -> W1T bf16 [256n][256k] ----------------
__global__ __launch_bounds__(256) void w1t_kernel(const float* __restrict__ W1,
                                                  unsigned short* __restrict__ W1T) {
    int k = blockIdx.x;
    int n = threadIdx.x;
    W1T[(size_t)n * 256 + k] = f2bf(W1[(size_t)k * 256 + n]);
}

// ---------------- GEMM1 MFMA: h1 = bf16(feat @ W1 + b1), output bf16 ----------------
#define LDA 40
__global__ __launch_bounds__(256) void gemm1_mfma(const float* __restrict__ A,
                                                  const unsigned short* __restrict__ BT,
                                                  const float* __restrict__ bias,
                                                  unsigned short* __restrict__ C) {
    __shared__ unsigned short As[128 * LDA];
    __shared__ unsigned short Bs[128 * LDA];
    int t = threadIdx.x;
    int lane = t & 63, wave = t >> 6;
    int ln = lane & 15, quad = lane >> 4;
    int row0 = blockIdx.x * 128;
    int col0 = blockIdx.y * 128;
    int m0 = (wave & 1) * 64, n0 = (wave >> 1) * 64;
    f32x4 acc[4][4];
    #pragma unroll
    for (int i = 0; i < 4; i++)
        #pragma unroll
        for (int j = 0; j < 4; j++) acc[i][j] = (f32x4){0.f, 0.f, 0.f, 0.f};
    int r = t >> 1, half = t & 1;

    for (int k0 = 0; k0 < 256; k0 += 32) {
        {
            int gr = row0 + r;
            float4 v[4];
            if (gr < N_NODES) {
                const float4* src = (const float4*)(A + (size_t)gr * 256 + k0 + half * 16);
                v[0] = src[0]; v[1] = src[1]; v[2] = src[2]; v[3] = src[3];
            } else {
                float4 z = make_float4(0.f, 0.f, 0.f, 0.f);
                v[0] = z; v[1] = z; v[2] = z; v[3] = z;
            }
            ushort4* dst = (ushort4*)&As[r * LDA + half * 16];
            #pragma unroll
            for (int q = 0; q < 4; q++) {
                ushort4 u;
                u.x = f2bf(v[q].x); u.y = f2bf(v[q].y);
                u.z = f2bf(v[q].z); u.w = f2bf(v[q].w);
                dst[q] = u;
            }
        }
        {
            const ushort4* src = (const ushort4*)(BT + (size_t)(col0 + r) * 256 + k0 + half * 16);
            ushort4* dst = (ushort4*)&Bs[r * LDA + half * 16];
            dst[0] = src[0]; dst[1] = src[1]; dst[2] = src[2]; dst[3] = src[3];
        }
        __syncthreads();
        Frag af[4], bf[4];
        #pragma unroll
        for (int i = 0; i < 4; i++) {
            int ar = m0 + i * 16 + ln;
            af[i].h[0] = *(const s16x4*)&As[ar * LDA + quad * 8];
            af[i].h[1] = *(const s16x4*)&As[ar * LDA + quad * 8 + 4];
            int br = n0 + i * 16 + ln;
            bf[i].h[0] = *(const s16x4*)&Bs[br * LDA + quad * 8];
            bf[i].h[1] = *(const s16x4*)&Bs[br * LDA + quad * 8 + 4];
        }
        #pragma unroll
        for (int i = 0; i < 4; i++)
            #pragma unroll
            for (int j = 0; j < 4; j++)
                acc[i][j] = __builtin_amdgcn_mfma_f32_16x16x32_bf16(af[i].v, bf[j].v, acc[i][j], 0, 0, 0);
        __syncthreads();
    }
    #pragma unroll
    for (int j = 0; j < 4; j++) {
        int gc = col0 + n0 + j * 16 + ln;
        float bv = bias[gc];
        #pragma unroll
        for (int i = 0; i < 4; i++) {
            int gb = row0 + m0 + i * 16 + quad * 4;
            #pragma unroll
            for (int rg = 0; rg < 4; rg++) {
                int gr = gb + rg;
                if (gr < N_NODES) C[(size_t)gr * 256 + gc] = f2bf(acc[i][j][rg] + bv);
            }
        }
    }
}

// ---------------- CSR build ----------------
__global__ __launch_bounds__(256) void hist_kernel(const int* __restrict__ ei,
                                                   int* __restrict__ cnt) {
    int e = blockIdx.x * 256 + threadIdx.x;
    if (e < N_EDGES) atomicAdd(&cnt[ei[N_EDGES + e]], 1);
}

__global__ __launch_bounds__(1024) void scan_kernel(const int* __restrict__ cnt,
                                                    int* __restrict__ offs) {
    __shared__ int sdata[1024];
    int t = threadIdx.x;
    const int CH = (N_NODES + 1023) / 1024;
    int base = t * CH;
    int s = 0;
    for (int i = 0; i < CH; i++) {
        int idx = base + i;
        if (idx < N_NODES) s += cnt[idx];
    }
    sdata[t] = s;
    __syncthreads();
    for (int off = 1; off < 1024; off <<= 1) {
        int v = (t >= off) ? sdata[t - off] : 0;
        __syncthreads();
        sdata[t] += v;
        __syncthreads();
    }
    int run = (t > 0) ? sdata[t - 1] : 0;
    for (int i = 0; i < CH; i++) {
        int idx = base + i;
        if (idx < N_NODES) {
            offs[idx] = run;
            run += cnt[idx];
        }
    }
    if (t == 1023) offs[N_NODES] = sdata[1023];
}

__global__ __launch_bounds__(256) void scatter_kernel(const int* __restrict__ ei,
                                                      const int* __restrict__ offs,
                                                      int* __restrict__ cur,
                                                      int* __restrict__ srcs) {
    int e = blockIdx.x * 256 + threadIdx.x;
    if (e >= N_EDGES) return;
    int d = ei[N_EDGES + e];
    int pos = offs[d] + atomicAdd(&cur[d], 1);
    srcs[pos] = ei[e];
}

// ---------------- agg1: wave per node, 4 edge-slots x 16 lanes ----------------
__global__ __launch_bounds__(256) void agg1_kernel(const unsigned short* __restrict__ h,
                                                   const int* __restrict__ offs,
                                                   const int* __restrict__ srcs,
                                                   const float* __restrict__ gamma_p,
                                                   float* __restrict__ x1) {
    int lane = threadIdx.x & 63;
    int node = blockIdx.x * 4 + (threadIdx.x >> 6);
    if (node >= N_NODES) return;
    int eslot = lane >> 4, cgrp = lane & 15;
    float g = gamma_p[0];
    float hd[16];
    {
        const uint4* hrow = (const uint4*)(h + (size_t)node * 256 + cgrp * 16);
        uint4 u0 = hrow[0], u1 = hrow[1];
        unpk8(u0, hd); unpk8(u1, hd + 8);
    }
    float acc[16];
    #pragma unroll
    for (int c = 0; c < 16; c++) acc[c] = 0.f;
    float den = 0.f;
    int beg = offs[node], end = offs[node + 1];
    int n_it = (end - beg + 3) >> 2;
    for (int it = 0; it < n_it; it++) {
        int i = beg + it * 4 + eslot;
        bool valid = i < end;
        int s = valid ? srcs[i] : node;
        const uint4* arow = (const uint4*)(h + (size_t)s * 256 + cgrp * 16);
        uint4 u0 = arow[0], u1 = arow[1];
        float av[16];
        unpk8(u0, av); unpk8(u1, av + 8);
        float d2 = 0.f;
        #pragma unroll
        for (int c = 0; c < 16; c++) { float d = av[c] - hd[c]; d2 = fmaf(d, d, d2); }
        d2 += __shfl_xor(d2, 1, 64);
        d2 += __shfl_xor(d2, 2, 64);
        d2 += __shfl_xor(d2, 4, 64);
        d2 += __shfl_xor(d2, 8, 64);
        float w = valid ? __expf(-g * d2) : 0.f;
        den += w;
        #pragma unroll
        for (int c = 0; c < 16; c++) acc[c] = fmaf(w, av[c], acc[c]);
    }
    #pragma unroll
    for (int m = 16; m < 64; m <<= 1) {
        den += __shfl_xor(den, m, 64);
        #pragma unroll
        for (int c = 0; c < 16; c++) acc[c] += __shfl_xor(acc[c], m, 64);
    }
    if (eslot == 0) {
        float inv = 1.f / (den + 1e-16f);
        float4* out = (float4*)(x1 + (size_t)node * 256 + cgrp * 16);
        #pragma unroll
        for (int q = 0; q < 4; q++)
            out[q] = make_float4(acc[q * 4 + 0] * inv, acc[q * 4 + 1] * inv,
                                 acc[q * 4 + 2] * inv, acc[q * 4 + 3] * inv);
    }
}

// ---------------- per-channel stats, C=256 ----------------
__global__ __launch_bounds__(256) void stats1_kernel(const float* __restrict__ x,
                                                     float* __restrict__ sum,
                                                     float* __restrict__ sumsq) {
    int c = threadIdx.x;
    float s = 0.f, s2 = 0.f;
    for (int r = blockIdx.x; r < N_NODES; r += gridDim.x) {
        float v = x[(size_t)r * 256 + c];
        s += v;
        s2 += v * v;
    }
    atomicAdd(&sum[c], s);
    atomicAdd(&sumsq[c], s2);
}

// ---------------- GEMM2 + fused BN1/ReLU: h2(stride 48) = relu(bn(x1)) @ W2 + b2 ----------------
__global__ __launch_bounds__(256) void gemm2_kernel(const float* __restrict__ X,
                                                    const float* __restrict__ W2,
                                                    const float* __restrict__ bias,
                                                    const float* __restrict__ sum1,
                                                    const float* __restrict__ sumsq1,
                                                    const float* __restrict__ bg,
                                                    const float* __restrict__ bb,
                                                    float* __restrict__ H) {
    __shared__ float W2s[40 * 260];
    __shared__ float aas[256], bbs[256];
    int t = threadIdx.x;
    for (int c = 0; c < 40; c++) W2s[c * 260 + t] = W2[(size_t)t * 40 + c];
    {
        const float invN = 1.f / N_NODES;
        float mu = sum1[t] * invN;
        float var = sumsq1[t] * invN - mu * mu;
        float rs = rsqrtf(var + 1e-5f) * bg[t];
        aas[t] = rs;
        bbs[t] = bb[t] - mu * rs;
    }
    __syncthreads();
    int slot = t >> 2, cg = t & 3;
    int rbase = blockIdx.x * 256 + slot;
    const float4* xp[4];
    #pragma unroll
    for (int rr = 0; rr < 4; rr++) xp[rr] = (const float4*)(X + (size_t)(rbase + rr * 64) * 256);
    float acc[4][10];
    #pragma unroll
    for (int rr = 0; rr < 4; rr++)
        #pragma unroll
        for (int i = 0; i < 10; i++) acc[rr][i] = 0.f;

    for (int k4 = 0; k4 < 64; k4++) {
        int k = k4 * 4;
        float4 a4 = *(const float4*)&aas[k];
        float4 b4 = *(const float4*)&bbs[k];
        float4 w4[10];
        #pragma unroll
        for (int i = 0; i < 10; i++) w4[i] = *(const float4*)&W2s[(cg * 10 + i) * 260 + k];
        #pragma unroll
        for (int rr = 0; rr < 4; rr++) {
            float4 xv = xp[rr][k4];
            float y0 = fmaxf(fmaf(xv.x, a4.x, b4.x), 0.f);
            float y1 = fmaxf(fmaf(xv.y, a4.y, b4.y), 0.f);
            float y2 = fmaxf(fmaf(xv.z, a4.z, b4.z), 0.f);
            float y3 = fmaxf(fmaf(xv.w, a4.w, b4.w), 0.f);
            #pragma unroll
            for (int i = 0; i < 10; i++)
                acc[rr][i] += y0 * w4[i].x + y1 * w4[i].y + y2 * w4[i].z + y3 * w4[i].w;
        }
    }
    #pragma unroll
    for (int rr = 0; rr < 4; rr++) {
        int row = rbase + rr * 64;
        if (row < N_NODES) {
            float* out = H + (size_t)row * H2S + cg * 10;
            #pragma unroll
            for (int i = 0; i < 10; i++) out[i] = acc[rr][i] + bias[cg * 10 + i];
        }
    }
}

// ---------------- agg2: wave per node, 8 edge-slots x 8 lanes (h2 stride 48, pad=0) ----------------
__global__ __launch_bounds__(256) void agg2_kernel(const float* __restrict__ h,
                                                   const int* __restrict__ offs,
                                                   const int* __restrict__ srcs,
                                                   const float* __restrict__ gamma_p,
                                                   float* __restrict__ x2) {
    int lane = threadIdx.x & 63;
    int node = blockIdx.x * 4 + (threadIdx.x >> 6);
    if (node >= N_NODES) return;
    int eslot = lane >> 3, cgrp = lane & 7;
    float g = gamma_p[0];
    float hd[6];
    {
        const float2* hrow = (const float2*)(h + (size_t)node * H2S + cgrp * 6);
        float2 a = hrow[0], b = hrow[1], c = hrow[2];
        hd[0] = a.x; hd[1] = a.y; hd[2] = b.x; hd[3] = b.y; hd[4] = c.x; hd[5] = c.y;
    }
    float acc[6] = {0.f, 0.f, 0.f, 0.f, 0.f, 0.f};
    float den = 0.f;
    int beg = offs[node], end = offs[node + 1];
    int n_it = (end - beg + 7) >> 3;
    for (int it = 0; it < n_it; it++) {
        int i = beg + it * 8 + eslot;
        bool valid = i < end;
        int s = valid ? srcs[i] : node;
        const float2* arow = (const float2*)(h + (size_t)s * H2S + cgrp * 6);
        float2 a = arow[0], b = arow[1], c = arow[2];
        float av[6];
        av[0] = a.x; av[1] = a.y; av[2] = b.x; av[3] = b.y; av[4] = c.x; av[5] = c.y;
        float d2 = 0.f;
        #pragma unroll
        for (int j = 0; j < 6; j++) { float d = av[j] - hd[j]; d2 = fmaf(d, d, d2); }
        d2 += __shfl_xor(d2, 1, 64);
        d2 += __shfl_xor(d2, 2, 64);
        d2 += __shfl_xor(d2, 4, 64);
        float w = valid ? __expf(-g * d2) : 0.f;
        den += w;
        #pragma unroll
        for (int j = 0; j < 6; j++) acc[j] = fmaf(w, av[j], acc[j]);
    }
    #pragma unroll
    for (int m = 8; m < 64; m <<= 1) {
        den += __shfl_xor(den, m, 64);
        #pragma unroll
        for (int j = 0; j < 6; j++) acc[j] += __shfl_xor(acc[j], m, 64);
    }
    if (eslot == 0) {
        float inv = 1.f / (den + 1e-16f);
        int cb = cgrp * 6;
        #pragma unroll
        for (int j = 0; j < 6; j++)
            if (cb + j < OUTC) x2[(size_t)node * OUTC + cb + j] = acc[j] * inv;
    }
}

// ---------------- per-channel stats, C=40 ----------------
__global__ __launch_bounds__(256) void stats2_kernel(const float* __restrict__ x,
                                                     float* __restrict__ sum,
                                                     float* __restrict__ sumsq) {
    int c = threadIdx.x;
    if (c >= OUTC) return;
    float s = 0.f, s2 = 0.f;
    for (int r = blockIdx.x * 4 + threadIdx.y; r < N_NODES; r += gridDim.x * 4) {
        float v = x[(size_t)r * OUTC + c];
        s += v;
        s2 += v * v;
    }
    atomicAdd(&sum[c], s);
    atomicAdd(&sumsq[c], s2);
}

// ---------------- BN2 + ReLU + gather + log_softmax ----------------
__global__ __launch_bounds__(256) void final_kernel(const float* __restrict__ x2,
                                                    const float* __restrict__ sum,
                                                    const float* __restrict__ sumsq,
                                                    const float* __restrict__ g,
                                                    const float* __restrict__ b,
                                                    const int* __restrict__ batch,
                                                    float* __restrict__ out) {
    int lane = threadIdx.x & 63;
    int row = blockIdx.x * 4 + (threadIdx.x >> 6);
    if (row >= N_BATCH) return;
    int node = batch[row];
    bool act = lane < OUTC;
    float v = -INFINITY;
    if (act) {
        const float invN = 1.f / N_NODES;
        float mu = sum[lane] * invN;
        float var = sumsq[lane] * invN - mu * mu;
        float xv = x2[(size_t)node * OUTC + lane];
        float y = (xv - mu) * rsqrtf(var + 1e-5f) * g[lane] + b[lane];
        v = fmaxf(y, 0.f);
    }
    float m = v;
    #pragma unroll
    for (int s = 1; s < 64; s <<= 1) m = fmaxf(m, __shfl_xor(m, s, 64));
    float p = act ? expf(v - m) : 0.f;
    float ssum = p;
    #pragma unroll
    for (int s = 1; s < 64; s <<= 1) ssum += __shfl_xor(ssum, s, 64);
    if (act) out[(size_t)row * OUTC + lane] = v - m - logf(ssum);
}

extern "C" void kernel_launch(void* const* d_in, const int* in_sizes, int n_in,
                              void* d_out, int out_size, void* d_ws, size_t ws_size,
                              hipStream_t stream) {
    const float* feat   = (const float*)d_in[0];
    const int*   ei     = (const int*)d_in[1];
    const int*   batch  = (const int*)d_in[2];
    const float* W1     = (const float*)d_in[3];
    const float* b1     = (const float*)d_in[4];
    const float* gamma1 = (const float*)d_in[5];
    const float* W2     = (const float*)d_in[6];
    const float* b2     = (const float*)d_in[7];
    const float* gamma2 = (const float*)d_in[8];
    const float* bn1w   = (const float*)d_in[9];
    const float* bn1b   = (const float*)d_in[10];
    const float* bn2w   = (const float*)d_in[11];
    const float* bn2b   = (const float*)d_in[12];

    char* ws = (char*)d_ws;
    // layout (aliased by liveness):
    //   [0, 25.6MB)      h1 bf16 [50000,256]   (later h2 fp32 [50000,48] = 9.6MB)
    //   [25.6, 76.8MB)   x1 fp32 [50000,256]   (later x2 fp32 [50000,40])
    //   [76.8MB, +128KB) W1T bf16 [256,256]
    //   [77.0MB ..)      offs / cnt / cur / srcs / stats
    unsigned short* h1  = (unsigned short*)ws;
    float* x1           = (float*)(ws + 25600000);
    unsigned short* w1t = (unsigned short*)(ws + 76800000);
    int* offs           = (int*)(ws + 77000000);
    int* cnt            = (int*)(ws + 77200064);
    int* cur            = (int*)(ws + 77400128);
    int* srcs           = (int*)(ws + 77600192);
    float* stats        = (float*)(ws + 80800256);
    float* sum1   = stats;
    float* sumsq1 = stats + 256;
    float* sum2   = stats + 512;
    float* sumsq2 = stats + 576;
    float* h2 = (float*)ws;
    float* x2 = x1;
    float* out = (float*)d_out;

    hipMemsetAsync(cnt, 0, N_NODES * 4, stream);
    hipMemsetAsync(cur, 0, N_NODES * 4, stream);
    hipMemsetAsync(stats, 0, 4096, stream);

    w1t_kernel<<<256, 256, 0, stream>>>(W1, w1t);
    hist_kernel<<<(N_EDGES + 255) / 256, 256, 0, stream>>>(ei, cnt);
    scan_kernel<<<1, 1024, 0, stream>>>(cnt, offs);
    scatter_kernel<<<(N_EDGES + 255) / 256, 256, 0, stream>>>(ei, offs, cur, srcs);

    // layer 1
    gemm1_mfma<<<dim3(391, 2), 256, 0, stream>>>(feat, w1t, b1, h1);
    agg1_kernel<<<(N_NODES + 3) / 4, 256, 0, stream>>>(h1, offs, srcs, gamma1, x1);
    stats1_kernel<<<512, 256, 0, stream>>>(x1, sum1, sumsq1);

    // layer 2 (BN1+ReLU fused into gemm2; h2 stride 48, pad zeroed for agg2)
    hipMemsetAsync(h2, 0, (size_t)N_NODES * H2S * 4, stream);
    gemm2_kernel<<<196, 256, 0, stream>>>(x1, W2, b2, sum1, sumsq1, bn1w, bn1b, h2);
    agg2_kernel<<<(N_NODES + 3) / 4, 256, 0, stream>>>(h2, offs, srcs, gamma2, x2);
    stats2_kernel<<<512, dim3(64, 4), 0, stream>>>(x2, sum2, sumsq2);
    final_kernel<<<(N_BATCH + 3) / 4, 256, 0, stream>>>(x2, sum2, sumsq2, bn2w, bn2b, batch, out);
}

// Round 5
// 441.972 us; speedup vs baseline: 8.5260x; 1.2069x over previous
//
#include <hip/hip_runtime.h>
#include <math.h>

#define N_NODES 50000
#define N_EDGES 800000
#define OUTC 40
#define N_BATCH 10000
#define H2S 48   // padded stride for h2
#define NBLK 196 // ceil(50000/256)

typedef float f32x4 __attribute__((ext_vector_type(4)));
typedef short s16x8 __attribute__((ext_vector_type(8)));
typedef short s16x4 __attribute__((ext_vector_type(4)));

union Frag { s16x8 v; s16x4 h[2]; };

__device__ inline unsigned short f2bf(float f) {
    unsigned int u = __float_as_uint(f);
    u += 0x7fff + ((u >> 16) & 1);           // round-to-nearest-even
    return (unsigned short)(u >> 16);
}
__device__ inline void unpk8(uint4 u, float* f) {   // 8 packed bf16 -> 8 fp32
    f[0] = __uint_as_float(u.x << 16); f[1] = __uint_as_float(u.x & 0xffff0000u);
    f[2] = __uint_as_float(u.y << 16); f[3] = __uint_as_float(u.y & 0xffff0000u);
    f[4] = __uint_as_float(u.z << 16); f[5] = __uint_as_float(u.z & 0xffff0000u);
    f[6] = __uint_as_float(u.w << 16); f[7] = __uint_as_float(u.w & 0xffff0000u);
}

// ---------------- W1 [256k][256n] fp32 -> W1T bf16 [256n][256k] ----------------
__global__ __launch_bounds__(256) void w1t_kernel(const float* __restrict__ W1,
                                                  unsigned short* __restrict__ W1T) {
    int k = blockIdx.x;
    int n = threadIdx.x;
    W1T[(size_t)n * 256 + k] = f2bf(W1[(size_t)k * 256 + n]);
}

// ---------------- GEMM1 MFMA: h1 = bf16(feat @ W1 + b1), output bf16 ----------------
#define LDA 40
__global__ __launch_bounds__(256) void gemm1_mfma(const float* __restrict__ A,
                                                  const unsigned short* __restrict__ BT,
                                                  const float* __restrict__ bias,
                                                  unsigned short* __restrict__ C) {
    __shared__ unsigned short As[128 * LDA];
    __shared__ unsigned short Bs[128 * LDA];
    int t = threadIdx.x;
    int lane = t & 63, wave = t >> 6;
    int ln = lane & 15, quad = lane >> 4;
    int row0 = blockIdx.x * 128;
    int col0 = blockIdx.y * 128;
    int m0 = (wave & 1) * 64, n0 = (wave >> 1) * 64;
    f32x4 acc[4][4];
    #pragma unroll
    for (int i = 0; i < 4; i++)
        #pragma unroll
        for (int j = 0; j < 4; j++) acc[i][j] = (f32x4){0.f, 0.f, 0.f, 0.f};
    int r = t >> 1, half = t & 1;

    for (int k0 = 0; k0 < 256; k0 += 32) {
        {
            int gr = row0 + r;
            float4 v[4];
            if (gr < N_NODES) {
                const float4* src = (const float4*)(A + (size_t)gr * 256 + k0 + half * 16);
                v[0] = src[0]; v[1] = src[1]; v[2] = src[2]; v[3] = src[3];
            } else {
                float4 z = make_float4(0.f, 0.f, 0.f, 0.f);
                v[0] = z; v[1] = z; v[2] = z; v[3] = z;
            }
            ushort4* dst = (ushort4*)&As[r * LDA + half * 16];
            #pragma unroll
            for (int q = 0; q < 4; q++) {
                ushort4 u;
                u.x = f2bf(v[q].x); u.y = f2bf(v[q].y);
                u.z = f2bf(v[q].z); u.w = f2bf(v[q].w);
                dst[q] = u;
            }
        }
        {
            const ushort4* src = (const ushort4*)(BT + (size_t)(col0 + r) * 256 + k0 + half * 16);
            ushort4* dst = (ushort4*)&Bs[r * LDA + half * 16];
            dst[0] = src[0]; dst[1] = src[1]; dst[2] = src[2]; dst[3] = src[3];
        }
        __syncthreads();
        Frag af[4], bf[4];
        #pragma unroll
        for (int i = 0; i < 4; i++) {
            int ar = m0 + i * 16 + ln;
            af[i].h[0] = *(const s16x4*)&As[ar * LDA + quad * 8];
            af[i].h[1] = *(const s16x4*)&As[ar * LDA + quad * 8 + 4];
            int br = n0 + i * 16 + ln;
            bf[i].h[0] = *(const s16x4*)&Bs[br * LDA + quad * 8];
            bf[i].h[1] = *(const s16x4*)&Bs[br * LDA + quad * 8 + 4];
        }
        #pragma unroll
        for (int i = 0; i < 4; i++)
            #pragma unroll
            for (int j = 0; j < 4; j++)
                acc[i][j] = __builtin_amdgcn_mfma_f32_16x16x32_bf16(af[i].v, bf[j].v, acc[i][j], 0, 0, 0);
        __syncthreads();
    }
    #pragma unroll
    for (int j = 0; j < 4; j++) {
        int gc = col0 + n0 + j * 16 + ln;
        float bv = bias[gc];
        #pragma unroll
        for (int i = 0; i < 4; i++) {
            int gb = row0 + m0 + i * 16 + quad * 4;
            #pragma unroll
            for (int rg = 0; rg < 4; rg++) {
                int gr = gb + rg;
                if (gr < N_NODES) C[(size_t)gr * 256 + gc] = f2bf(acc[i][j][rg] + bv);
            }
        }
    }
}

// ---------------- CSR build ----------------
__global__ __launch_bounds__(256) void hist_kernel(const int* __restrict__ ei,
                                                   int* __restrict__ cnt) {
    int e = blockIdx.x * 256 + threadIdx.x;
    if (e < N_EDGES) atomicAdd(&cnt[ei[N_EDGES + e]], 1);
}

// hierarchical scan: block sums -> scan of block sums -> per-block scan + offset
__global__ __launch_bounds__(256) void bsum_kernel(const int* __restrict__ cnt,
                                                   int* __restrict__ bsum) {
    __shared__ int s[256];
    int t = threadIdx.x;
    int i = blockIdx.x * 256 + t;
    s[t] = (i < N_NODES) ? cnt[i] : 0;
    __syncthreads();
    for (int off = 128; off > 0; off >>= 1) {
        if (t < off) s[t] += s[t + off];
        __syncthreads();
    }
    if (t == 0) bsum[blockIdx.x] = s[0];
}

__global__ __launch_bounds__(256) void bscan_kernel(const int* __restrict__ bsum,
                                                    int* __restrict__ bpre) {
    __shared__ int s[256];
    int t = threadIdx.x;
    s[t] = (t < NBLK) ? bsum[t] : 0;
    __syncthreads();
    for (int off = 1; off < 256; off <<= 1) {
        int v = (t >= off) ? s[t - off] : 0;
        __syncthreads();
        s[t] += v;
        __syncthreads();
    }
    if (t < NBLK) bpre[t] = (t > 0) ? s[t - 1] : 0;
}

__global__ __launch_bounds__(256) void blockscan_kernel(const int* __restrict__ cnt,
                                                        const int* __restrict__ bpre,
                                                        int* __restrict__ offs) {
    __shared__ int s[256];
    int t = threadIdx.x;
    int i = blockIdx.x * 256 + t;
    s[t] = (i < N_NODES) ? cnt[i] : 0;
    __syncthreads();
    for (int off = 1; off < 256; off <<= 1) {
        int v = (t >= off) ? s[t - off] : 0;
        __syncthreads();
        s[t] += v;
        __syncthreads();
    }
    int excl = (t > 0) ? s[t - 1] : 0;
    int base = bpre[blockIdx.x];
    if (i < N_NODES) offs[i] = base + excl;
    if (i == N_NODES - 1) offs[N_NODES] = base + s[t];
}

__global__ __launch_bounds__(256) void scatter_kernel(const int* __restrict__ ei,
                                                      const int* __restrict__ offs,
                                                      int* __restrict__ cur,
                                                      int* __restrict__ srcs) {
    int e = blockIdx.x * 256 + threadIdx.x;
    if (e >= N_EDGES) return;
    int d = ei[N_EDGES + e];
    int pos = offs[d] + atomicAdd(&cur[d], 1);
    srcs[pos] = ei[e];
}

// ---------------- agg1: wave per node, 4 edge-slots x 16 lanes ----------------
__global__ __launch_bounds__(256) void agg1_kernel(const unsigned short* __restrict__ h,
                                                   const int* __restrict__ offs,
                                                   const int* __restrict__ srcs,
                                                   const float* __restrict__ gamma_p,
                                                   float* __restrict__ x1) {
    int lane = threadIdx.x & 63;
    int node = blockIdx.x * 4 + (threadIdx.x >> 6);
    if (node >= N_NODES) return;
    int eslot = lane >> 4, cgrp = lane & 15;
    float g = gamma_p[0];
    float hd[16];
    {
        const uint4* hrow = (const uint4*)(h + (size_t)node * 256 + cgrp * 16);
        uint4 u0 = hrow[0], u1 = hrow[1];
        unpk8(u0, hd); unpk8(u1, hd + 8);
    }
    float acc[16];
    #pragma unroll
    for (int c = 0; c < 16; c++) acc[c] = 0.f;
    float den = 0.f;
    int beg = offs[node], end = offs[node + 1];
    int n_it = (end - beg + 3) >> 2;
    for (int it = 0; it < n_it; it++) {
        int i = beg + it * 4 + eslot;
        bool valid = i < end;
        int s = valid ? srcs[i] : node;
        const uint4* arow = (const uint4*)(h + (size_t)s * 256 + cgrp * 16);
        uint4 u0 = arow[0], u1 = arow[1];
        float av[16];
        unpk8(u0, av); unpk8(u1, av + 8);
        float d2 = 0.f;
        #pragma unroll
        for (int c = 0; c < 16; c++) { float d = av[c] - hd[c]; d2 = fmaf(d, d, d2); }
        d2 += __shfl_xor(d2, 1, 64);
        d2 += __shfl_xor(d2, 2, 64);
        d2 += __shfl_xor(d2, 4, 64);
        d2 += __shfl_xor(d2, 8, 64);
        float w = valid ? __expf(-g * d2) : 0.f;
        den += w;
        #pragma unroll
        for (int c = 0; c < 16; c++) acc[c] = fmaf(w, av[c], acc[c]);
    }
    #pragma unroll
    for (int m = 16; m < 64; m <<= 1) {
        den += __shfl_xor(den, m, 64);
        #pragma unroll
        for (int c = 0; c < 16; c++) acc[c] += __shfl_xor(acc[c], m, 64);
    }
    if (eslot == 0) {
        float inv = 1.f / (den + 1e-16f);
        float4* out = (float4*)(x1 + (size_t)node * 256 + cgrp * 16);
        #pragma unroll
        for (int q = 0; q < 4; q++)
            out[q] = make_float4(acc[q * 4 + 0] * inv, acc[q * 4 + 1] * inv,
                                 acc[q * 4 + 2] * inv, acc[q * 4 + 3] * inv);
    }
}

// ---------------- per-channel stats, C=256 ----------------
__global__ __launch_bounds__(256) void stats1_kernel(const float* __restrict__ x,
                                                     float* __restrict__ sum,
                                                     float* __restrict__ sumsq) {
    int c = threadIdx.x;
    float s = 0.f, s2 = 0.f;
    for (int r = blockIdx.x; r < N_NODES; r += gridDim.x) {
        float v = x[(size_t)r * 256 + c];
        s += v;
        s2 += v * v;
    }
    atomicAdd(&sum[c], s);
    atomicAdd(&sumsq[c], s2);
}

// ---------------- GEMM2 + fused BN1/ReLU: h2(stride 48) = relu(bn(x1)) @ W2 + b2 ----------------
__global__ __launch_bounds__(256) void gemm2_kernel(const float* __restrict__ X,
                                                    const float* __restrict__ W2,
                                                    const float* __restrict__ bias,
                                                    const float* __restrict__ sum1,
                                                    const float* __restrict__ sumsq1,
                                                    const float* __restrict__ bg,
                                                    const float* __restrict__ bb,
                                                    float* __restrict__ H) {
    __shared__ float W2s[40 * 260];
    __shared__ float aas[256], bbs[256];
    int t = threadIdx.x;
    for (int c = 0; c < 40; c++) W2s[c * 260 + t] = W2[(size_t)t * 40 + c];
    {
        const float invN = 1.f / N_NODES;
        float mu = sum1[t] * invN;
        float var = sumsq1[t] * invN - mu * mu;
        float rs = rsqrtf(var + 1e-5f) * bg[t];
        aas[t] = rs;
        bbs[t] = bb[t] - mu * rs;
    }
    __syncthreads();
    int slot = t >> 2, cg = t & 3;
    int rbase = blockIdx.x * 256 + slot;
    const float4* xp[4];
    #pragma unroll
    for (int rr = 0; rr < 4; rr++) xp[rr] = (const float4*)(X + (size_t)(rbase + rr * 64) * 256);
    float acc[4][10];
    #pragma unroll
    for (int rr = 0; rr < 4; rr++)
        #pragma unroll
        for (int i = 0; i < 10; i++) acc[rr][i] = 0.f;

    for (int k4 = 0; k4 < 64; k4++) {
        int k = k4 * 4;
        float4 a4 = *(const float4*)&aas[k];
        float4 b4 = *(const float4*)&bbs[k];
        float4 w4[10];
        #pragma unroll
        for (int i = 0; i < 10; i++) w4[i] = *(const float4*)&W2s[(cg * 10 + i) * 260 + k];
        #pragma unroll
        for (int rr = 0; rr < 4; rr++) {
            float4 xv = xp[rr][k4];
            float y0 = fmaxf(fmaf(xv.x, a4.x, b4.x), 0.f);
            float y1 = fmaxf(fmaf(xv.y, a4.y, b4.y), 0.f);
            float y2 = fmaxf(fmaf(xv.z, a4.z, b4.z), 0.f);
            float y3 = fmaxf(fmaf(xv.w, a4.w, b4.w), 0.f);
            #pragma unroll
            for (int i = 0; i < 10; i++)
                acc[rr][i] += y0 * w4[i].x + y1 * w4[i].y + y2 * w4[i].z + y3 * w4[i].w;
        }
    }
    #pragma unroll
    for (int rr = 0; rr < 4; rr++) {
        int row = rbase + rr * 64;
        if (row < N_NODES) {
            float* out = H + (size_t)row * H2S + cg * 10;
            #pragma unroll
            for (int i = 0; i < 10; i++) out[i] = acc[rr][i] + bias[cg * 10 + i];
        }
    }
}

// ---------------- agg2: wave per node, 8 edge-slots x 8 lanes (h2 stride 48, pad=0) ----------------
__global__ __launch_bounds__(256) void agg2_kernel(const float* __restrict__ h,
                                                   const int* __restrict__ offs,
                                                   const int* __restrict__ srcs,
                                                   const float* __restrict__ gamma_p,
                                                   float* __restrict__ x2) {
    int lane = threadIdx.x & 63;
    int node = blockIdx.x * 4 + (threadIdx.x >> 6);
    if (node >= N_NODES) return;
    int eslot = lane >> 3, cgrp = lane & 7;
    float g = gamma_p[0];
    float hd[6];
    {
        const float2* hrow = (const float2*)(h + (size_t)node * H2S + cgrp * 6);
        float2 a = hrow[0], b = hrow[1], c = hrow[2];
        hd[0] = a.x; hd[1] = a.y; hd[2] = b.x; hd[3] = b.y; hd[4] = c.x; hd[5] = c.y;
    }
    float acc[6] = {0.f, 0.f, 0.f, 0.f, 0.f, 0.f};
    float den = 0.f;
    int beg = offs[node], end = offs[node + 1];
    int n_it = (end - beg + 7) >> 3;
    for (int it = 0; it < n_it; it++) {
        int i = beg + it * 8 + eslot;
        bool valid = i < end;
        int s = valid ? srcs[i] : node;
        const float2* arow = (const float2*)(h + (size_t)s * H2S + cgrp * 6);
        float2 a = arow[0], b = arow[1], c = arow[2];
        float av[6];
        av[0] = a.x; av[1] = a.y; av[2] = b.x; av[3] = b.y; av[4] = c.x; av[5] = c.y;
        float d2 = 0.f;
        #pragma unroll
        for (int j = 0; j < 6; j++) { float d = av[j] - hd[j]; d2 = fmaf(d, d, d2); }
        d2 += __shfl_xor(d2, 1, 64);
        d2 += __shfl_xor(d2, 2, 64);
        d2 += __shfl_xor(d2, 4, 64);
        float w = valid ? __expf(-g * d2) : 0.f;
        den += w;
        #pragma unroll
        for (int j = 0; j < 6; j++) acc[j] = fmaf(w, av[j], acc[j]);
    }
    #pragma unroll
    for (int m = 8; m < 64; m <<= 1) {
        den += __shfl_xor(den, m, 64);
        #pragma unroll
        for (int j = 0; j < 6; j++) acc[j] += __shfl_xor(acc[j], m, 64);
    }
    if (eslot == 0) {
        float inv = 1.f / (den + 1e-16f);
        int cb = cgrp * 6;
        #pragma unroll
        for (int j = 0; j < 6; j++)
            if (cb + j < OUTC) x2[(size_t)node * OUTC + cb + j] = acc[j] * inv;
    }
}

// ---------------- per-channel stats, C=40 ----------------
__global__ __launch_bounds__(256) void stats2_kernel(const float* __restrict__ x,
                                                     float* __restrict__ sum,
                                                     float* __restrict__ sumsq) {
    int c = threadIdx.x;
    if (c >= OUTC) return;
    float s = 0.f, s2 = 0.f;
    for (int r = blockIdx.x * 4 + threadIdx.y; r < N_NODES; r += gridDim.x * 4) {
        float v = x[(size_t)r * OUTC + c];
        s += v;
        s2 += v * v;
    }
    atomicAdd(&sum[c], s);
    atomicAdd(&sumsq[c], s2);
}

// ---------------- BN2 + ReLU + gather + log_softmax ----------------
__global__ __launch_bounds__(256) void final_kernel(const float* __restrict__ x2,
                                                    const float* __restrict__ sum,
                                                    const float* __restrict__ sumsq,
                                                    const float* __restrict__ g,
                                                    const float* __restrict__ b,
                                                    const int* __restrict__ batch,
                                                    float* __restrict__ out) {
    int lane = threadIdx.x & 63;
    int row = blockIdx.x * 4 + (threadIdx.x >> 6);
    if (row >= N_BATCH) return;
    int node = batch[row];
    bool act = lane < OUTC;
    float v = -INFINITY;
    if (act) {
        const float invN = 1.f / N_NODES;
        float mu = sum[lane] * invN;
        float var = sumsq[lane] * invN - mu * mu;
        float xv = x2[(size_t)node * OUTC + lane];
        float y = (xv - mu) * rsqrtf(var + 1e-5f) * g[lane] + b[lane];
        v = fmaxf(y, 0.f);
    }
    float m = v;
    #pragma unroll
    for (int s = 1; s < 64; s <<= 1) m = fmaxf(m, __shfl_xor(m, s, 64));
    float p = act ? expf(v - m) : 0.f;
    float ssum = p;
    #pragma unroll
    for (int s = 1; s < 64; s <<= 1) ssum += __shfl_xor(ssum, s, 64);
    if (act) out[(size_t)row * OUTC + lane] = v - m - logf(ssum);
}

extern "C" void kernel_launch(void* const* d_in, const int* in_sizes, int n_in,
                              void* d_out, int out_size, void* d_ws, size_t ws_size,
                              hipStream_t stream) {
    const float* feat   = (const float*)d_in[0];
    const int*   ei     = (const int*)d_in[1];
    const int*   batch  = (const int*)d_in[2];
    const float* W1     = (const float*)d_in[3];
    const float* b1     = (const float*)d_in[4];
    const float* gamma1 = (const float*)d_in[5];
    const float* W2     = (const float*)d_in[6];
    const float* b2     = (const float*)d_in[7];
    const float* gamma2 = (const float*)d_in[8];
    const float* bn1w   = (const float*)d_in[9];
    const float* bn1b   = (const float*)d_in[10];
    const float* bn2w   = (const float*)d_in[11];
    const float* bn2b   = (const float*)d_in[12];

    char* ws = (char*)d_ws;
    // layout (aliased by liveness):
    //   [0, 25.6MB)      h1 bf16 [50000,256]   (later h2 fp32 [50000,48] = 9.6MB)
    //   [25.6, 76.8MB)   x1 fp32 [50000,256]   (later x2 fp32 [50000,40])
    //   [76.8MB, +128KB) W1T bf16 [256,256]
    //   [77.0MB ..)      offs / cnt / cur / srcs / bsum / bpre / stats
    unsigned short* h1  = (unsigned short*)ws;
    float* x1           = (float*)(ws + 25600000);
    unsigned short* w1t = (unsigned short*)(ws + 76800000);
    int* offs           = (int*)(ws + 77000000);
    int* cnt            = (int*)(ws + 77200064);
    int* cur            = (int*)(ws + 77400128);
    int* srcs           = (int*)(ws + 77600192);
    int* bsum           = (int*)(ws + 80800256);
    int* bpre           = (int*)(ws + 80801280);
    float* stats        = (float*)(ws + 80802304);
    float* sum1   = stats;
    float* sumsq1 = stats + 256;
    float* sum2   = stats + 512;
    float* sumsq2 = stats + 576;
    float* h2 = (float*)ws;
    float* x2 = x1;
    float* out = (float*)d_out;

    hipMemsetAsync(cnt, 0, N_NODES * 4, stream);
    hipMemsetAsync(cur, 0, N_NODES * 4, stream);
    hipMemsetAsync(stats, 0, 4096, stream);

    w1t_kernel<<<256, 256, 0, stream>>>(W1, w1t);
    hist_kernel<<<(N_EDGES + 255) / 256, 256, 0, stream>>>(ei, cnt);
    bsum_kernel<<<NBLK, 256, 0, stream>>>(cnt, bsum);
    bscan_kernel<<<1, 256, 0, stream>>>(bsum, bpre);
    blockscan_kernel<<<NBLK, 256, 0, stream>>>(cnt, bpre, offs);
    scatter_kernel<<<(N_EDGES + 255) / 256, 256, 0, stream>>>(ei, offs, cur, srcs);

    // layer 1
    gemm1_mfma<<<dim3(391, 2), 256, 0, stream>>>(feat, w1t, b1, h1);
    agg1_kernel<<<(N_NODES + 3) / 4, 256, 0, stream>>>(h1, offs, srcs, gamma1, x1);
    stats1_kernel<<<512, 256, 0, stream>>>(x1, sum1, sumsq1);

    // layer 2 (BN1+ReLU fused into gemm2; h2 stride 48, pad zeroed for agg2)
    hipMemsetAsync(h2, 0, (size_t)N_NODES * H2S * 4, stream);
    gemm2_kernel<<<196, 256, 0, stream>>>(x1, W2, b2, sum1, sumsq1, bn1w, bn1b, h2);
    agg2_kernel<<<(N_NODES + 3) / 4, 256, 0, stream>>>(h2, offs, srcs, gamma2, x2);
    stats2_kernel<<<512, dim3(64, 4), 0, stream>>>(x2, sum2, sumsq2);
    final_kernel<<<(N_BATCH + 3) / 4, 256, 0, stream>>>(x2, sum2, sumsq2, bn2w, bn2b, batch, out);
}